// Round 2
// baseline (1284.069 us; speedup 1.0000x reference)
//
#include <hip/hip_runtime.h>
#include <stdint.h>
#include <stddef.h>

#define NTOK 8192
#define DM 1024
#define DF 4096
#define NE 8
#define TM 128
#define TN 128
#define BK 64
#define MAXTILE 144
#define CNTSTR 32                   // cnt[e] at cnt[e*CNTSTR] -> 128 B apart (atomic contention fix)
#define SMHALF (TM * BK)            // 8192 u16 = 16 KB
#define SMSIZE ((TM + TN) * BK)     // 16384 u16 = 32 KB single buffer -> 4 blocks/CU

typedef unsigned short u16;
typedef __attribute__((ext_vector_type(8))) short bf16x8;
typedef __attribute__((ext_vector_type(8))) unsigned short u16x8;
typedef __attribute__((ext_vector_type(4))) float f32x4;

__device__ __forceinline__ u16 f2bf(float f) {
  union { float f; unsigned u; } v; v.f = f;
  unsigned r = v.u + 0x7fffu + ((v.u >> 16) & 1u);
  return (u16)(r >> 16);
}

__device__ __forceinline__ void async_copy16(const void* g, void* l) {
  __builtin_amdgcn_global_load_lds((const __attribute__((address_space(1))) void*)g,
                                   (__attribute__((address_space(3))) void*)l, 16, 0, 0);
}

__device__ __forceinline__ void raw_barrier() {
  __asm__ volatile("s_barrier" ::: "memory");
}
__device__ __forceinline__ void wait_vm0() {
  __asm__ volatile("s_waitcnt vmcnt(0)" ::: "memory");
}

// Bijective XCD-chunk remap (requires nwg % 8 == 0, true for both GEMM grids):
// consecutive dispatch ids round-robin across XCDs; this gives each XCD a
// contiguous chunk of the flat (tile-major, panel-inner) iteration space so the
// A-tile is reused from the XCD's own L2 across all N-panels and H is fetched
// from HBM ~once.
__device__ __forceinline__ int xcd_flat() {
  int nwg  = (int)(gridDim.x * gridDim.y);
  int orig = (int)(blockIdx.y * gridDim.x + blockIdx.x);
  int q = nwg >> 3;
  return (orig & 7) * q + (orig >> 3);
}

// ---------- transpose + cast weights: w [E][R][C] fp32 -> wt [E][C][R] bf16 ----------
// Write phase vectorized: ushort8 (16 B) stores; LDS column reads at stride 33
// floats are 2-way conflicts max (33*8 = 264 == 8 mod 32) = free.
__global__ __launch_bounds__(256) void k_transpose_cast(const float* __restrict__ w, u16* __restrict__ wt,
                                                        int R, int C) {
  __shared__ float tile[32][33];
  size_t base = (size_t)blockIdx.z * R * C;
  const float* wb = w + base;
  u16* wtb = wt + base;
  int c0 = blockIdx.x * 32, r0 = blockIdx.y * 32;
  int tx = threadIdx.x & 31, ty = threadIdx.x >> 5;
#pragma unroll
  for (int i = 0; i < 4; i++)
    tile[ty + i * 8][tx] = wb[(size_t)(r0 + ty + i * 8) * C + (c0 + tx)];
  __syncthreads();
  if (threadIdx.x < 128) {
    int oc = threadIdx.x >> 2;   // wt row = c0 + oc
    int ow = threadIdx.x & 3;    // which 8-wide chunk of the 32 r's
    u16x8 o;
#pragma unroll
    for (int j = 0; j < 8; j++) o[j] = f2bf(tile[ow * 8 + j][oc]);
    *(u16x8*)&wtb[(size_t)(c0 + oc) * R + (r0 + ow * 8)] = o;
  }
}

// ---------- gating (fused x fp32->bf16 cast: saves a full 33 MB re-read) ----------
__global__ __launch_bounds__(256) void k_gate(const float* __restrict__ x, const float* __restrict__ gw,
                                              const float* __restrict__ gb, int* __restrict__ cnt,
                                              int* __restrict__ lidx, float* __restrict__ lw,
                                              u16* __restrict__ xb) {
  int wave = threadIdx.x >> 6, lane = threadIdx.x & 63;
  int tok = blockIdx.x * 4 + wave;
  const float* xr = x + (size_t)tok * DM;
  u16* xbr = xb + (size_t)tok * DM;
  float acc[NE];
#pragma unroll
  for (int e = 0; e < NE; e++) acc[e] = 0.f;
  for (int d = lane; d < DM; d += 64) {
    float xv = xr[d];
    xbr[d] = f2bf(xv);
    const float* g = gw + d * NE;
#pragma unroll
    for (int e = 0; e < NE; e++) acc[e] += xv * g[e];
  }
#pragma unroll
  for (int off = 32; off > 0; off >>= 1) {
#pragma unroll
    for (int e = 0; e < NE; e++) acc[e] += __shfl_down(acc[e], off);
  }
  if (lane == 0) {
    float l[NE], m = -1e30f;
#pragma unroll
    for (int e = 0; e < NE; e++) { l[e] = acc[e] + gb[e]; m = l[e] > m ? l[e] : m; }
    float p[NE], s = 0.f;
#pragma unroll
    for (int e = 0; e < NE; e++) { p[e] = expf(l[e] - m); s += p[e]; }
    float inv = 1.f / s;
    int e0 = 0; float s0 = p[0];
#pragma unroll
    for (int e = 1; e < NE; e++) if (p[e] > s0) { s0 = p[e]; e0 = e; }
    int e1 = -1; float s1 = -1.f;
#pragma unroll
    for (int e = 0; e < NE; e++) if (e != e0 && p[e] > s1) { s1 = p[e]; e1 = e; }
    s0 *= inv; s1 *= inv;
    int pos0 = atomicAdd(&cnt[e0 * CNTSTR], 1);
    lidx[e0 * NTOK + pos0] = tok; lw[e0 * NTOK + pos0] = s0;
    int pos1 = atomicAdd(&cnt[e1 * CNTSTR], 1);
    lidx[e1 * NTOK + pos1] = tok; lw[e1 * NTOK + pos1] = s1;
  }
}

// ---------- scan + row-tile map: tmap[t] = (e<<16) | rowTileWithinExpert ----------
__global__ __launch_bounds__(256) void k_scan(const int* __restrict__ cnt, int* __restrict__ off,
                                              int* __restrict__ tmap, int* __restrict__ ntile) {
  __shared__ int soff[NE], stile[NE + 1];
  if (threadIdx.x == 0) {
    int s = 0, t = 0;
    for (int e = 0; e < NE; e++) {
      soff[e] = s; stile[e] = t;
      t += (cnt[e * CNTSTR] + TM - 1) / TM;
      s += cnt[e * CNTSTR];
    }
    stile[NE] = t; ntile[0] = t;
  }
  __syncthreads();
  if (threadIdx.x < NE) off[threadIdx.x] = soff[threadIdx.x];
  for (int i = threadIdx.x; i < MAXTILE; i += 256) {
    if (i < stile[NE]) {
      int e = 0;
      while (stile[e + 1] <= i) e++;
      tmap[i] = (e << 16) | (i - stile[e]);
    }
  }
}

// LDS tile layout: element (row, k) at u16 offset row*BK + ((kc ^ (row&7))<<3) + (k&7),
// swizzle on the GLOBAL source address, undone at ds_read (2-way max = free).
// SINGLE buffer (m97 structure): STAGE -> vmcnt(0) -> barrier -> MFMA -> barrier.
// 32 KB LDS/block + __launch_bounds__(256,4) -> 4 blocks/CU (was 2 with dbuf):
// the load latency is hidden by block-level TLP, not intra-block prefetch
// (m97 874 TF vs m99/m100 dbuf 839-890 TF on the same 128^2 structure).

#define STAGE                                                           \
  do {                                                                  \
    _Pragma("unroll") for (int i = 0; i < 4; i++) {                     \
      async_copy16(aPtr[i], smAll + (wave * 4 + i) * 512);              \
      async_copy16(bPtr[i], smAll + SMHALF + (wave * 4 + i) * 512);     \
      aPtr[i] += BK; bPtr[i] += BK;                                     \
    }                                                                   \
  } while (0)

#define COMPUTE                                                             \
  do {                                                                      \
    const u16* bufA = smAll;                                                \
    const u16* bufB = smAll + SMHALF;                                       \
    _Pragma("unroll") for (int h = 0; h < 2; h++) {                         \
      const int koff = h ? koff1 : koff0;                                   \
      bf16x8 af[4], bfr[4];                                                 \
      _Pragma("unroll") for (int mt = 0; mt < 4; mt++)                      \
        af[mt] = *(const bf16x8*)&bufA[offA[mt] + koff];                    \
      _Pragma("unroll") for (int nt = 0; nt < 4; nt++)                      \
        bfr[nt] = *(const bf16x8*)&bufB[offB[nt] + koff];                   \
      _Pragma("unroll") for (int mt = 0; mt < 4; mt++)                      \
        _Pragma("unroll") for (int nt = 0; nt < 4; nt++)                    \
          acc[mt][nt] = __builtin_amdgcn_mfma_f32_16x16x32_bf16(af[mt], bfr[nt], acc[mt][nt], 0, 0, 0); \
    }                                                                       \
  } while (0)

#define FRAG_SETUP                                                      \
  const int waveM = wave >> 1, waveN = wave & 1;                        \
  const int c15 = lane & 15, quad = lane >> 4;                          \
  const int r7 = c15 & 7;                                               \
  const int koff0 = ((quad ^ r7) & 7) << 3;                             \
  const int koff1 = (((4 + quad) ^ r7) & 7) << 3;                       \
  int offA[4], offB[4];                                                 \
  _Pragma("unroll") for (int i = 0; i < 4; i++) {                       \
    offA[i] = (waveM * 64 + i * 16 + c15) * BK;                         \
    offB[i] = (waveN * 64 + i * 16 + c15) * BK;                         \
  }

// ---------- GEMM1: H[pair, f] = relu(Xb[idx] @ W1t^T + b1)  (K = DM) ----------
__global__ __launch_bounds__(256, 4) void k_gemm1(const u16* __restrict__ xb, const u16* __restrict__ w1t,
                                                  const float* __restrict__ b1, u16* __restrict__ H,
                                                  const int* __restrict__ cnt, const int* __restrict__ offp,
                                                  const int* __restrict__ lidx, const int* __restrict__ tmap,
                                                  const int* __restrict__ ntile) {
  const int flat = xcd_flat();
  const int tileIdx = flat >> 5;          // 32 N-panels
  if (tileIdx >= ntile[0]) return;
  const int me = tmap[tileIdx];
  const int e = me >> 16;
  const int t0 = (me & 0xffff) * TM;
  const int c = cnt[e * CNTSTR];
  const int n0 = (flat & 31) * TN;

  __shared__ __align__(16) u16 smAll[SMSIZE];

  const int tid = threadIdx.x;
  const int wave = tid >> 6, lane = tid & 63;
  const int sr = lane >> 3;
  const int skb = (((lane & 7) ^ sr) & 7) * 8;

  const u16* aPtr[4]; const u16* bPtr[4];
#pragma unroll
  for (int i = 0; i < 4; i++) {
    int row = (wave * 4 + i) * 8 + sr;
    int p = t0 + row; p = p < c ? p : c - 1;
    int tk = lidx[e * NTOK + p];
    aPtr[i] = xb + (size_t)tk * DM + skb;
    bPtr[i] = w1t + ((size_t)e * DF + (n0 + row)) * DM + skb;
  }

  FRAG_SETUP

  f32x4 acc[4][4];
#pragma unroll
  for (int mt = 0; mt < 4; mt++)
#pragma unroll
    for (int nt = 0; nt < 4; nt++) acc[mt][nt] = 0.f;

  for (int k0 = 0; k0 < DM; k0 += BK) {
    STAGE;
    wait_vm0();
    raw_barrier();
    COMPUTE;
    raw_barrier();
  }

  // Epilogue via LDS (loop's trailing barrier protects the reuse), 16B stores.
  u16* st = smAll;
  const int hoff = offp[e];
#pragma unroll
  for (int mt = 0; mt < 4; mt++)
#pragma unroll
    for (int r = 0; r < 4; r++) {
      int rowLoc = waveM * 64 + mt * 16 + quad * 4 + r;
#pragma unroll
      for (int nt = 0; nt < 4; nt++) {
        int colLoc = waveN * 64 + nt * 16 + c15;
        float v = acc[mt][nt][r] + b1[e * DF + n0 + colLoc];
        st[rowLoc * TN + colLoc] = f2bf(v > 0.f ? v : 0.f);
      }
    }
  __syncthreads();
#pragma unroll
  for (int it = 0; it < 8; it++) {
    int id = it * 256 + tid;
    int row = id >> 4, c16 = id & 15;
    int p = t0 + row;
    if (p < c)
      *(bf16x8*)&H[(size_t)(hoff + p) * DF + n0 + c16 * 8] =
          *(const bf16x8*)&st[row * TN + c16 * 8];
  }
}

// ---------- GEMM2: out[tok, d] += s * (H @ W2t^T + b2)  (K = DF) ----------
__global__ __launch_bounds__(256, 4) void k_gemm2(const u16* __restrict__ H, const u16* __restrict__ w2t,
                                                  const float* __restrict__ b2, float* __restrict__ out,
                                                  const int* __restrict__ cnt, const int* __restrict__ offp,
                                                  const int* __restrict__ lidx, const float* __restrict__ lw,
                                                  const int* __restrict__ tmap, const int* __restrict__ ntile) {
  const int flat = xcd_flat();
  const int tileIdx = flat >> 3;          // 8 N-panels
  if (tileIdx >= ntile[0]) return;
  const int me = tmap[tileIdx];
  const int e = me >> 16;
  const int t0 = (me & 0xffff) * TM;
  const int c = cnt[e * CNTSTR];
  const int n0 = (flat & 7) * TN;
  const int hoff = offp[e];

  __shared__ __align__(16) u16 smAll[SMSIZE];

  const int tid = threadIdx.x;
  const int wave = tid >> 6, lane = tid & 63;
  const int sr = lane >> 3;
  const int skb = (((lane & 7) ^ sr) & 7) * 8;

  const u16* aPtr[4]; const u16* bPtr[4];
#pragma unroll
  for (int i = 0; i < 4; i++) {
    int row = (wave * 4 + i) * 8 + sr;
    int p = t0 + row; p = p < c ? p : c - 1;
    aPtr[i] = H + (size_t)(hoff + p) * DF + skb;
    bPtr[i] = w2t + ((size_t)e * DM + (n0 + row)) * DF + skb;
  }

  FRAG_SETUP

  f32x4 acc[4][4];
#pragma unroll
  for (int mt = 0; mt < 4; mt++)
#pragma unroll
    for (int nt = 0; nt < 4; nt++) acc[mt][nt] = 0.f;

  for (int k0 = 0; k0 < DF; k0 += BK) {
    STAGE;
    wait_vm0();
    raw_barrier();
    COMPUTE;
    raw_barrier();
  }

#pragma unroll
  for (int mt = 0; mt < 4; mt++) {
#pragma unroll
    for (int r = 0; r < 4; r++) {
      int rowLoc = waveM * 64 + mt * 16 + quad * 4 + r;
      int p = t0 + rowLoc;
      if (p < c) {
        int tok = lidx[e * NTOK + p];
        float wgt = lw[e * NTOK + p];
#pragma unroll
        for (int nt = 0; nt < 4; nt++) {
          int col = n0 + waveN * 64 + nt * 16 + c15;
          float v = wgt * (acc[mt][nt][r] + b2[e * DM + col]);
          atomicAdd(&out[(size_t)tok * DM + col], v);
        }
      }
    }
  }
}

extern "C" void kernel_launch(void* const* d_in, const int* in_sizes, int n_in,
                              void* d_out, int out_size, void* d_ws, size_t ws_size,
                              hipStream_t stream) {
  const float* x  = (const float*)d_in[0];
  const float* gw = (const float*)d_in[1];
  const float* gb = (const float*)d_in[2];
  const float* w1 = (const float*)d_in[3];
  const float* b1 = (const float*)d_in[4];
  const float* w2 = (const float*)d_in[5];
  const float* b2 = (const float*)d_in[6];
  float* out = (float*)d_out;

  char* ws = (char*)d_ws;
  u16* xb    = (u16*)(ws);
  u16* wT    = (u16*)(ws + 16777216);
  u16* H     = (u16*)(ws + 16777216 + 67108864);
  char* sm   = ws + 16777216 + 67108864 + 134217728;
  int* lidx  = (int*)(sm);
  float* lw  = (float*)(sm + 262144);
  int* cnt   = (int*)(sm + 524288);            // NE*CNTSTR ints = 1 KB
  int* offp  = (int*)(sm + 524288 + 1024);
  int* tmap  = (int*)(sm + 524288 + 1024 + 128);
  int* ntile = (int*)(sm + 524288 + 1024 + 128 + MAXTILE * 4);

  hipMemsetAsync(cnt, 0, NE * CNTSTR * sizeof(int), stream);
  hipMemsetAsync(out, 0, (size_t)out_size * sizeof(float), stream);

  k_gate<<<NTOK / 4, 256, 0, stream>>>(x, gw, gb, cnt, lidx, lw, xb);
  k_scan<<<1, 256, 0, stream>>>(cnt, offp, tmap, ntile);

  // W1 [E][DM][DF] -> w1t [E][DF][DM]
  k_transpose_cast<<<dim3(DF / 32, DM / 32, NE), 256, 0, stream>>>(w1, wT, DM, DF);
  k_gemm1<<<dim3(MAXTILE, DF / TN), 256, 0, stream>>>(xb, wT, b1, H, cnt, offp, lidx, tmap, ntile);

  // W2 [E][DF][DM] -> w2t [E][DM][DF]
  k_transpose_cast<<<dim3(DM / 32, DF / 32, NE), 256, 0, stream>>>(w2, wT, DF, DM);
  k_gemm2<<<dim3(MAXTILE, DM / TN), 256, 0, stream>>>(H, wT, b2, out, cnt, offp, lidx, lw, tmap, ntile);
}

// Round 4
// 777.771 us; speedup vs baseline: 1.6510x; 1.6510x over previous
//
#include <hip/hip_runtime.h>
#include <stdint.h>
#include <stddef.h>

#define NTOK 8192
#define DM 1024
#define DF 4096
#define NE 8
#define TM 128
#define TN 128
#define BK 64
#define MAXTILE 144
#define CNTSTR 32                   // cnt[e] at cnt[e*CNTSTR] -> 128 B apart (atomic contention fix)
#define SMHALF (TM * BK)            // 8192 u16 = 16 KB
#define SMSIZE ((TM + TN) * BK)     // 16384 u16 = 32 KB single buffer

typedef unsigned short u16;
typedef __attribute__((ext_vector_type(8))) short bf16x8;
typedef __attribute__((ext_vector_type(8))) unsigned short u16x8;
typedef __attribute__((ext_vector_type(4))) float f32x4;

__device__ __forceinline__ u16 f2bf(float f) {
  union { float f; unsigned u; } v; v.f = f;
  unsigned r = v.u + 0x7fffu + ((v.u >> 16) & 1u);
  return (u16)(r >> 16);
}

__device__ __forceinline__ void async_copy16(const void* g, void* l) {
  __builtin_amdgcn_global_load_lds((const __attribute__((address_space(1))) void*)g,
                                   (__attribute__((address_space(3))) void*)l, 16, 0, 0);
}

// Bijective XCD-chunk remap (requires nwg % 8 == 0, true for both GEMM grids):
// consecutive dispatch ids round-robin across XCDs; this gives each XCD a
// contiguous chunk of the flat (tile-major, panel-inner) iteration space so the
// A-tile is reused from the XCD's own L2 across all N-panels and H is fetched
// from HBM ~once (r0->r1: FETCH 700 -> 270 MB).
__device__ __forceinline__ int xcd_flat() {
  int nwg  = (int)(gridDim.x * gridDim.y);
  int orig = (int)(blockIdx.y * gridDim.x + blockIdx.x);
  int q = nwg >> 3;
  return (orig & 7) * q + (orig >> 3);
}

// ---------- transpose + cast weights: w [E][R][C] fp32 -> wt [E][C][R] bf16 ----------
// Write phase vectorized: ushort8 (16 B) stores; LDS column reads at stride 33
// floats are 2-way conflicts max = free.
__global__ __launch_bounds__(256) void k_transpose_cast(const float* __restrict__ w, u16* __restrict__ wt,
                                                        int R, int C) {
  __shared__ float tile[32][33];
  size_t base = (size_t)blockIdx.z * R * C;
  const float* wb = w + base;
  u16* wtb = wt + base;
  int c0 = blockIdx.x * 32, r0 = blockIdx.y * 32;
  int tx = threadIdx.x & 31, ty = threadIdx.x >> 5;
#pragma unroll
  for (int i = 0; i < 4; i++)
    tile[ty + i * 8][tx] = wb[(size_t)(r0 + ty + i * 8) * C + (c0 + tx)];
  __syncthreads();
  if (threadIdx.x < 128) {
    int oc = threadIdx.x >> 2;   // wt row = c0 + oc
    int ow = threadIdx.x & 3;    // which 8-wide chunk of the 32 r's
    u16x8 o;
#pragma unroll
    for (int j = 0; j < 8; j++) o[j] = f2bf(tile[ow * 8 + j][oc]);
    *(u16x8*)&wtb[(size_t)(c0 + oc) * R + (r0 + ow * 8)] = o;
  }
}

// ---------- gating (fused x fp32->bf16 cast: saves a full 33 MB re-read) ----------
__global__ __launch_bounds__(256) void k_gate(const float* __restrict__ x, const float* __restrict__ gw,
                                              const float* __restrict__ gb, int* __restrict__ cnt,
                                              int* __restrict__ lidx, float* __restrict__ lw,
                                              u16* __restrict__ xb) {
  int wave = threadIdx.x >> 6, lane = threadIdx.x & 63;
  int tok = blockIdx.x * 4 + wave;
  const float* xr = x + (size_t)tok * DM;
  u16* xbr = xb + (size_t)tok * DM;
  float acc[NE];
#pragma unroll
  for (int e = 0; e < NE; e++) acc[e] = 0.f;
  for (int d = lane; d < DM; d += 64) {
    float xv = xr[d];
    xbr[d] = f2bf(xv);
    const float* g = gw + d * NE;
#pragma unroll
    for (int e = 0; e < NE; e++) acc[e] += xv * g[e];
  }
#pragma unroll
  for (int off = 32; off > 0; off >>= 1) {
#pragma unroll
    for (int e = 0; e < NE; e++) acc[e] += __shfl_down(acc[e], off);
  }
  if (lane == 0) {
    float l[NE], m = -1e30f;
#pragma unroll
    for (int e = 0; e < NE; e++) { l[e] = acc[e] + gb[e]; m = l[e] > m ? l[e] : m; }
    float p[NE], s = 0.f;
#pragma unroll
    for (int e = 0; e < NE; e++) { p[e] = expf(l[e] - m); s += p[e]; }
    float inv = 1.f / s;
    int e0 = 0; float s0 = p[0];
#pragma unroll
    for (int e = 1; e < NE; e++) if (p[e] > s0) { s0 = p[e]; e0 = e; }
    int e1 = -1; float s1 = -1.f;
#pragma unroll
    for (int e = 0; e < NE; e++) if (e != e0 && p[e] > s1) { s1 = p[e]; e1 = e; }
    s0 *= inv; s1 *= inv;
    int pos0 = atomicAdd(&cnt[e0 * CNTSTR], 1);
    lidx[e0 * NTOK + pos0] = tok; lw[e0 * NTOK + pos0] = s0;
    int pos1 = atomicAdd(&cnt[e1 * CNTSTR], 1);
    lidx[e1 * NTOK + pos1] = tok; lw[e1 * NTOK + pos1] = s1;
  }
}

// ---------- scan + row-tile map: tmap[t] = (e<<16) | rowTileWithinExpert ----------
__global__ __launch_bounds__(256) void k_scan(const int* __restrict__ cnt, int* __restrict__ off,
                                              int* __restrict__ tmap, int* __restrict__ ntile) {
  __shared__ int soff[NE], stile[NE + 1];
  if (threadIdx.x == 0) {
    int s = 0, t = 0;
    for (int e = 0; e < NE; e++) {
      soff[e] = s; stile[e] = t;
      t += (cnt[e * CNTSTR] + TM - 1) / TM;
      s += cnt[e * CNTSTR];
    }
    stile[NE] = t; ntile[0] = t;
  }
  __syncthreads();
  if (threadIdx.x < NE) off[threadIdx.x] = soff[threadIdx.x];
  for (int i = threadIdx.x; i < MAXTILE; i += 256) {
    if (i < stile[NE]) {
      int e = 0;
      while (stile[e + 1] <= i) e++;
      tmap[i] = (e << 16) | (i - stile[e]);
    }
  }
}

// LDS tile layout: element (row, k) at u16 offset row*BK + ((kc ^ (row&7))<<3) + (k&7),
// swizzle on the GLOBAL source address, undone at ds_read (2-way max = free).
// SINGLE buffer, EXACT m97 sync structure:
//   STAGE -> __syncthreads() -> COMPUTE -> __syncthreads()
// __syncthreads (NOT raw s_barrier) is load-bearing: it emits
// s_waitcnt vmcnt(0) lgkmcnt(0) before s_barrier, draining the global_load_lds
// DMA and all ds_reads before any wave reuses the buffer. Round 3's bare
// s_barrier version had a codegen-dependent race (passed only when (256,4)
// spill traffic incidentally serialized it; failed clean at (256,3)).
// __launch_bounds__(256,3): reg cap ~170 >= the ~152 needed -> no spill
// (the (256,4) cap of 128 spilled: WRITE_SIZE 65->640 MB in round 2);
// 32 KB LDS -> occupancy VGPR-limited at 3 blocks/CU = 12 waves/CU = m97 config.

#define STAGE                                                           \
  do {                                                                  \
    _Pragma("unroll") for (int i = 0; i < 4; i++) {                     \
      async_copy16(aPtr[i], smAll + (wave * 4 + i) * 512);              \
      async_copy16(bPtr[i], smAll + SMHALF + (wave * 4 + i) * 512);     \
      aPtr[i] += BK; bPtr[i] += BK;                                     \
    }                                                                   \
  } while (0)

#define COMPUTE                                                             \
  do {                                                                      \
    const u16* bufA = smAll;                                                \
    const u16* bufB = smAll + SMHALF;                                       \
    _Pragma("unroll") for (int h = 0; h < 2; h++) {                         \
      const int koff = h ? koff1 : koff0;                                   \
      bf16x8 af[4], bfr[4];                                                 \
      _Pragma("unroll") for (int mt = 0; mt < 4; mt++)                      \
        af[mt] = *(const bf16x8*)&bufA[offA[mt] + koff];                    \
      _Pragma("unroll") for (int nt = 0; nt < 4; nt++)                      \
        bfr[nt] = *(const bf16x8*)&bufB[offB[nt] + koff];                   \
      _Pragma("unroll") for (int mt = 0; mt < 4; mt++)                      \
        _Pragma("unroll") for (int nt = 0; nt < 4; nt++)                    \
          acc[mt][nt] = __builtin_amdgcn_mfma_f32_16x16x32_bf16(af[mt], bfr[nt], acc[mt][nt], 0, 0, 0); \
    }                                                                       \
  } while (0)

#define FRAG_SETUP                                                      \
  const int waveM = wave >> 1, waveN = wave & 1;                        \
  const int c15 = lane & 15, quad = lane >> 4;                          \
  const int r7 = c15 & 7;                                               \
  const int koff0 = ((quad ^ r7) & 7) << 3;                             \
  const int koff1 = (((4 + quad) ^ r7) & 7) << 3;                       \
  int offA[4], offB[4];                                                 \
  _Pragma("unroll") for (int i = 0; i < 4; i++) {                       \
    offA[i] = (waveM * 64 + i * 16 + c15) * BK;                         \
    offB[i] = (waveN * 64 + i * 16 + c15) * BK;                         \
  }

// ---------- GEMM1: H[pair, f] = relu(Xb[idx] @ W1t^T + b1)  (K = DM) ----------
__global__ __launch_bounds__(256, 3) void k_gemm1(const u16* __restrict__ xb, const u16* __restrict__ w1t,
                                                  const float* __restrict__ b1, u16* __restrict__ H,
                                                  const int* __restrict__ cnt, const int* __restrict__ offp,
                                                  const int* __restrict__ lidx, const int* __restrict__ tmap,
                                                  const int* __restrict__ ntile) {
  const int flat = xcd_flat();
  const int tileIdx = flat >> 5;          // 32 N-panels
  if (tileIdx >= ntile[0]) return;
  const int me = tmap[tileIdx];
  const int e = me >> 16;
  const int t0 = (me & 0xffff) * TM;
  const int c = cnt[e * CNTSTR];
  const int n0 = (flat & 31) * TN;

  __shared__ __align__(16) u16 smAll[SMSIZE];

  const int tid = threadIdx.x;
  const int wave = tid >> 6, lane = tid & 63;
  const int sr = lane >> 3;
  const int skb = (((lane & 7) ^ sr) & 7) * 8;

  const u16* aPtr[4]; const u16* bPtr[4];
#pragma unroll
  for (int i = 0; i < 4; i++) {
    int row = (wave * 4 + i) * 8 + sr;
    int p = t0 + row; p = p < c ? p : c - 1;
    int tk = lidx[e * NTOK + p];
    aPtr[i] = xb + (size_t)tk * DM + skb;
    bPtr[i] = w1t + ((size_t)e * DF + (n0 + row)) * DM + skb;
  }

  FRAG_SETUP

  f32x4 acc[4][4];
#pragma unroll
  for (int mt = 0; mt < 4; mt++)
#pragma unroll
    for (int nt = 0; nt < 4; nt++) acc[mt][nt] = 0.f;

  for (int k0 = 0; k0 < DM; k0 += BK) {
    STAGE;
    __syncthreads();
    COMPUTE;
    __syncthreads();
  }

  // Epilogue via LDS (loop's trailing __syncthreads drained everything), 16B stores.
  u16* st = smAll;
  const int hoff = offp[e];
#pragma unroll
  for (int mt = 0; mt < 4; mt++)
#pragma unroll
    for (int r = 0; r < 4; r++) {
      int rowLoc = waveM * 64 + mt * 16 + quad * 4 + r;
#pragma unroll
      for (int nt = 0; nt < 4; nt++) {
        int colLoc = waveN * 64 + nt * 16 + c15;
        float v = acc[mt][nt][r] + b1[e * DF + n0 + colLoc];
        st[rowLoc * TN + colLoc] = f2bf(v > 0.f ? v : 0.f);
      }
    }
  __syncthreads();
#pragma unroll
  for (int it = 0; it < 8; it++) {
    int id = it * 256 + tid;
    int row = id >> 4, c16 = id & 15;
    int p = t0 + row;
    if (p < c)
      *(bf16x8*)&H[(size_t)(hoff + p) * DF + n0 + c16 * 8] =
          *(const bf16x8*)&st[row * TN + c16 * 8];
  }
}

// ---------- GEMM2: out[tok, d] += s * (H @ W2t^T + b2)  (K = DF) ----------
__global__ __launch_bounds__(256, 3) void k_gemm2(const u16* __restrict__ H, const u16* __restrict__ w2t,
                                                  const float* __restrict__ b2, float* __restrict__ out,
                                                  const int* __restrict__ cnt, const int* __restrict__ offp,
                                                  const int* __restrict__ lidx, const float* __restrict__ lw,
                                                  const int* __restrict__ tmap, const int* __restrict__ ntile) {
  const int flat = xcd_flat();
  const int tileIdx = flat >> 3;          // 8 N-panels
  if (tileIdx >= ntile[0]) return;
  const int me = tmap[tileIdx];
  const int e = me >> 16;
  const int t0 = (me & 0xffff) * TM;
  const int c = cnt[e * CNTSTR];
  const int n0 = (flat & 7) * TN;
  const int hoff = offp[e];

  __shared__ __align__(16) u16 smAll[SMSIZE];

  const int tid = threadIdx.x;
  const int wave = tid >> 6, lane = tid & 63;
  const int sr = lane >> 3;
  const int skb = (((lane & 7) ^ sr) & 7) * 8;

  const u16* aPtr[4]; const u16* bPtr[4];
#pragma unroll
  for (int i = 0; i < 4; i++) {
    int row = (wave * 4 + i) * 8 + sr;
    int p = t0 + row; p = p < c ? p : c - 1;
    aPtr[i] = H + (size_t)(hoff + p) * DF + skb;
    bPtr[i] = w2t + ((size_t)e * DM + (n0 + row)) * DF + skb;
  }

  FRAG_SETUP

  f32x4 acc[4][4];
#pragma unroll
  for (int mt = 0; mt < 4; mt++)
#pragma unroll
    for (int nt = 0; nt < 4; nt++) acc[mt][nt] = 0.f;

  for (int k0 = 0; k0 < DF; k0 += BK) {
    STAGE;
    __syncthreads();
    COMPUTE;
    __syncthreads();
  }

#pragma unroll
  for (int mt = 0; mt < 4; mt++) {
#pragma unroll
    for (int r = 0; r < 4; r++) {
      int rowLoc = waveM * 64 + mt * 16 + quad * 4 + r;
      int p = t0 + rowLoc;
      if (p < c) {
        int tok = lidx[e * NTOK + p];
        float wgt = lw[e * NTOK + p];
#pragma unroll
        for (int nt = 0; nt < 4; nt++) {
          int col = n0 + waveN * 64 + nt * 16 + c15;
          float v = wgt * (acc[mt][nt][r] + b2[e * DM + col]);
          atomicAdd(&out[(size_t)tok * DM + col], v);
        }
      }
    }
  }
}

extern "C" void kernel_launch(void* const* d_in, const int* in_sizes, int n_in,
                              void* d_out, int out_size, void* d_ws, size_t ws_size,
                              hipStream_t stream) {
  const float* x  = (const float*)d_in[0];
  const float* gw = (const float*)d_in[1];
  const float* gb = (const float*)d_in[2];
  const float* w1 = (const float*)d_in[3];
  const float* b1 = (const float*)d_in[4];
  const float* w2 = (const float*)d_in[5];
  const float* b2 = (const float*)d_in[6];
  float* out = (float*)d_out;

  char* ws = (char*)d_ws;
  u16* xb    = (u16*)(ws);
  u16* wT    = (u16*)(ws + 16777216);
  u16* H     = (u16*)(ws + 16777216 + 67108864);
  char* sm   = ws + 16777216 + 67108864 + 134217728;
  int* lidx  = (int*)(sm);
  float* lw  = (float*)(sm + 262144);
  int* cnt   = (int*)(sm + 524288);            // NE*CNTSTR ints = 1 KB
  int* offp  = (int*)(sm + 524288 + 1024);
  int* tmap  = (int*)(sm + 524288 + 1024 + 128);
  int* ntile = (int*)(sm + 524288 + 1024 + 128 + MAXTILE * 4);

  hipMemsetAsync(cnt, 0, NE * CNTSTR * sizeof(int), stream);
  hipMemsetAsync(out, 0, (size_t)out_size * sizeof(float), stream);

  k_gate<<<NTOK / 4, 256, 0, stream>>>(x, gw, gb, cnt, lidx, lw, xb);
  k_scan<<<1, 256, 0, stream>>>(cnt, offp, tmap, ntile);

  // W1 [E][DM][DF] -> w1t [E][DF][DM]
  k_transpose_cast<<<dim3(DF / 32, DM / 32, NE), 256, 0, stream>>>(w1, wT, DM, DF);
  k_gemm1<<<dim3(MAXTILE, DF / TN), 256, 0, stream>>>(xb, wT, b1, H, cnt, offp, lidx, tmap, ntile);

  // W2 [E][DF][DM] -> w2t [E][DM][DF]
  k_transpose_cast<<<dim3(DM / 32, DF / 32, NE), 256, 0, stream>>>(w2, wT, DF, DM);
  k_gemm2<<<dim3(MAXTILE, DM / TN), 256, 0, stream>>>(H, wT, b2, out, cnt, offp, lidx, lw, tmap, ntile);
}